// Round 2
// baseline (325.265 us; speedup 1.0000x reference)
//
#include <hip/hip_runtime.h>

// ---------------------------------------------------------------------------
// Fused equivariant NLMP edge kernel, fp32, MI355X.
// Phase A: per-edge compute -> dense edge_out[E][32] (no atomics).
// Phase B: CSR build (hist/scan/fill) + per-node coalesced gather-sum.
// Fallback to fp32-atomic scatter if ws_size is too small.
// ---------------------------------------------------------------------------

#define EPB   64          // edges per block
#define BLOCK (EPB * 8)   // 512 threads

#define SQRT3_F      1.7320508075688772f
#define INV_SQRT3_F  0.5773502691896258f
#define INV_SQRT10_F 0.31622776601683794f
#define A1_4         0.044194173824159216f   // (1/sqrt(32)) * (1/4)
#define A2_4         0.0625f                 // (1/sqrt(16)) * (1/4)

__global__ void zero_i32(int* __restrict__ p, int n) {
    int i = blockIdx.x * blockDim.x + threadIdx.x;
    if (i < n) p[i] = 0;
}
__global__ void zero_f32(float* __restrict__ p, int n) {
    int i = blockIdx.x * blockDim.x + threadIdx.x;
    if (i < n) p[i] = 0.0f;
}

__global__ void hist_dst(const int* __restrict__ edst, int* __restrict__ counts, int E) {
    int e = blockIdx.x * blockDim.x + threadIdx.x;
    if (e < E) atomicAdd(&counts[edst[e]], 1);
}

// single-block exclusive scan over counts -> offsets (and cursor copy)
__global__ void scan_offsets(const int* __restrict__ counts, int* __restrict__ offsets,
                             int* __restrict__ cursor, int nn) {
    __shared__ int buf[1024];
    __shared__ int base_s;
    const int tid = threadIdx.x;
    if (tid == 0) base_s = 0;
    __syncthreads();
    for (int start = 0; start < nn; start += 1024) {
        const int i = start + tid;
        const int v = (i < nn) ? counts[i] : 0;
        buf[tid] = v;
        __syncthreads();
        #pragma unroll
        for (int off = 1; off < 1024; off <<= 1) {
            int t = (tid >= off) ? buf[tid - off] : 0;
            __syncthreads();
            buf[tid] += t;
            __syncthreads();
        }
        const int excl = buf[tid] - v + base_s;
        if (i < nn) { offsets[i] = excl; cursor[i] = excl; }
        __syncthreads();
        if (tid == 1023) base_s += buf[1023];
        __syncthreads();
    }
}

__global__ void fill_csr(const int* __restrict__ edst, int* __restrict__ cursor,
                         int* __restrict__ eidx, int E) {
    int e = blockIdx.x * blockDim.x + threadIdx.x;
    if (e < E) {
        int p = atomicAdd(&cursor[edst[e]], 1);
        eidx[p] = e;
    }
}

// 32 threads per node: coalesced 128B reads of edge_out, one plain store
__global__ void gather_out(const float* __restrict__ eout, const int* __restrict__ offsets,
                           const int* __restrict__ counts, const int* __restrict__ eidx,
                           float* __restrict__ out, int nn) {
    const int tid = threadIdx.x;
    const int n = blockIdx.x * 8 + (tid >> 5);
    const int t = tid & 31;
    if (n >= nn) return;
    const int beg = offsets[n];
    const int cnt = counts[n];
    float acc = 0.0f;
    for (int k = 0; k < cnt; ++k) {
        const int idx = eidx[beg + k];
        acc += eout[(size_t)idx * 32 + t];
    }
    out[(size_t)n * 32 + t] = acc;
}

static __device__ __forceinline__ float dot16(const float4 a, const float4 b,
                                              const float4 c, const float4 d,
                                              const float* __restrict__ w) {
    const float4 w0 = *(const float4*)(w + 0);
    const float4 w1 = *(const float4*)(w + 4);
    const float4 w2 = *(const float4*)(w + 8);
    const float4 w3 = *(const float4*)(w + 12);
    return a.x*w0.x + a.y*w0.y + a.z*w0.z + a.w*w0.w
         + b.x*w1.x + b.y*w1.y + b.z*w1.z + b.w*w1.w
         + c.x*w2.x + c.y*w2.y + c.z*w2.z + c.w*w2.w
         + d.x*w3.x + d.y*w3.y + d.z*w3.z + d.w*w3.w;
}

// ATOMIC=0: write per-edge outputs to eout[E][32]; ATOMIC=1: atomicAdd into out[N][32]
template <int ATOMIC>
__global__ void __launch_bounds__(BLOCK, 2) eq_nlmp(
    const float* __restrict__ x,        // [N,32]
    const int*   __restrict__ esrc,     // [E]
    const int*   __restrict__ edst,     // [E]
    const float* __restrict__ evec,     // [E,3]
    const float* __restrict__ emb,      // [E,10]
    const float* __restrict__ nrm,      // [E]
    const float* __restrict__ W1,       // [10,16]
    const float* __restrict__ W2,       // [16,512]
    const float* __restrict__ W3,       // [10,16]
    const float* __restrict__ W4,       // [16,384]
    float*       __restrict__ dst_buf,  // eout [E,32]  (or out [N,32] if ATOMIC)
    int E)
{
    __shared__ float sW [512 * 20];   // phase1: W2^T rows [512][20]; phase2: W4^T rows [384][20]
    __shared__ float sW1[160];
    __shared__ float sW3[160];
    __shared__ float sXP[EPB * 68];   // per edge: xs[0..31], xd at +32 (stride 68 = 16B aligned)
    __shared__ float sEM[EPB * 10];
    __shared__ float sSH[EPB * 3];
    __shared__ float sH [EPB * 20];
    __shared__ float sST[EPB * 8];
    __shared__ float sVT[EPB * 24];

    const int tid = threadIdx.x;
    const int e   = tid >> 3;
    const int j   = tid & 7;
    int ge        = blockIdx.x * EPB + e;
    const bool act = (ge < E);
    if (!act) ge = E - 1;

    // ---- stage phase-1 weights: sW[q*20+h] = W2[h][q] ----
    for (int idx = tid; idx < 8192; idx += BLOCK) {
        int h = idx >> 9, q = idx & 511;
        sW[q * 20 + h] = W2[idx];
    }
    if (tid < 160) { sW1[tid] = W1[tid]; sW3[tid] = W3[tid]; }

    // ---- per-edge data loads ----
    const int src = esrc[ge];
    const int dst = edst[ge];
    {
        const float4* xs4 = (const float4*)(x + (size_t)src * 32);
        const float4* xd4 = (const float4*)(x + (size_t)dst * 32);
        float4 a = xs4[j];
        float4 b = xd4[j];
        *(float4*)&sXP[e * 68 + 4 * j]      = a;
        *(float4*)&sXP[e * 68 + 32 + 4 * j] = b;
    }
    if (j < 5) {
        float2 t = *(const float2*)(emb + (size_t)ge * 10 + 2 * j);
        *(float2*)&sEM[e * 10 + 2 * j] = t;
    }
    if (j == 0) {
        float vx = evec[(size_t)ge * 3 + 0];
        float vy = evec[(size_t)ge * 3 + 1];
        float vz = evec[(size_t)ge * 3 + 2];
        float rn = sqrtf(vx * vx + vy * vy + vz * vz);
        sSH[e * 3 + 0] = SQRT3_F * vx / rn;
        sSH[e * 3 + 1] = SQRT3_F * vy / rn;
        sSH[e * 3 + 2] = SQRT3_F * vz / rn;
    }
    __syncthreads();

    // ---- h1 = relu(emb @ W1 / sqrt(10)) ----
    #pragma unroll
    for (int t = 0; t < 2; ++t) {
        const int hid = j + 8 * t;
        float acc = 0.0f;
        #pragma unroll
        for (int i = 0; i < 10; ++i) acc += sEM[e * 10 + i] * sW1[i * 16 + hid];
        sH[e * 20 + hid] = fmaxf(acc * INV_SQRT10_F, 0.0f);
    }
    __syncthreads();

    const float sh0 = sSH[e * 3 + 0], sh1 = sSH[e * 3 + 1], sh2 = sSH[e * 3 + 2];

    // ---- TP1 ----
    float sts = 0.0f, svs = 0.0f, vt0 = 0.0f, vt1 = 0.0f, vt2 = 0.0f;
    {
        const float4 ha = *(const float4*)&sH[e * 20 + 0];
        const float4 hb = *(const float4*)&sH[e * 20 + 4];
        const float4 hc = *(const float4*)&sH[e * 20 + 8];
        const float4 hd = *(const float4*)&sH[e * 20 + 12];
        for (int u = 0; u < 16; ++u) {
            const int so = (u < 8) ? u : (u + 24);
            const int vo = (u < 8) ? (8 + 3 * u) : (16 + 3 * u);
            const float su = sXP[e * 68 + so];
            const float a0 = sXP[e * 68 + vo + 0];
            const float a1 = sXP[e * 68 + vo + 1];
            const float a2 = sXP[e * 68 + vo + 2];
            const float vd = (a0 * sh0 + a1 * sh1 + a2 * sh2) * INV_SQRT3_F;
            const float* wb = &sW[(u * 8 + j) * 20];
            const float wss = dot16(ha, hb, hc, hd, wb);
            const float wvv = dot16(ha, hb, hc, hd, wb + 128 * 20);
            const float wsv = dot16(ha, hb, hc, hd, wb + 256 * 20);
            const float wvs = dot16(ha, hb, hc, hd, wb + 384 * 20);
            sts += su * wss + vd * wvv;
            svs += su * wsv;
            vt0 += a0 * wvs;
            vt1 += a1 * wvs;
            vt2 += a2 * wvs;
        }
    }
    sST[e * 8 + j] = sts * A1_4;
    const float vtx = (svs * sh0 + vt0) * A1_4;
    const float vty = (svs * sh1 + vt1) * A1_4;
    const float vtz = (svs * sh2 + vt2) * A1_4;
    sVT[e * 24 + 3 * j + 0] = vtx;
    sVT[e * 24 + 3 * j + 1] = vty;
    sVT[e * 24 + 3 * j + 2] = vtz;
    __syncthreads();

    // ---- stage phase-2 weights + h2 ----
    #pragma unroll 4
    for (int h = 0; h < 16; ++h) {
        if (tid < 384) sW[tid * 20 + h] = W4[h * 384 + tid];
    }
    #pragma unroll
    for (int t = 0; t < 2; ++t) {
        const int hid = j + 8 * t;
        float acc = 0.0f;
        #pragma unroll
        for (int i = 0; i < 10; ++i) acc += sEM[e * 10 + i] * sW3[i * 16 + hid];
        sH[e * 20 + hid] = fmaxf(acc * INV_SQRT10_F, 0.0f);
    }
    __syncthreads();

    // ---- TP2 ----
    float scal = 0.0f, gat = 0.0f, csv = 0.0f, vv0 = 0.0f, vv1 = 0.0f, vv2 = 0.0f;
    {
        const float4 ha = *(const float4*)&sH[e * 20 + 0];
        const float4 hb = *(const float4*)&sH[e * 20 + 4];
        const float4 hc = *(const float4*)&sH[e * 20 + 8];
        const float4 hd = *(const float4*)&sH[e * 20 + 12];
        for (int u = 0; u < 8; ++u) {
            const float su = sST[e * 8 + u];
            const float b0 = sVT[e * 24 + 3 * u + 0];
            const float b1 = sVT[e * 24 + 3 * u + 1];
            const float b2 = sVT[e * 24 + 3 * u + 2];
            const float vd = (b0 * sh0 + b1 * sh1 + b2 * sh2) * INV_SQRT3_F;
            const float* wb = &sW[(u * 8 + j) * 20];
            const float wA  = dot16(ha, hb, hc, hd, wb);
            const float wAv = dot16(ha, hb, hc, hd, wb +  64 * 20);
            const float wB  = dot16(ha, hb, hc, hd, wb + 128 * 20);
            const float wBv = dot16(ha, hb, hc, hd, wb + 192 * 20);
            const float wC  = dot16(ha, hb, hc, hd, wb + 256 * 20);
            const float wCv = dot16(ha, hb, hc, hd, wb + 320 * 20);
            scal += su * wA + vd * wAv;
            gat  += su * wB + vd * wBv;
            csv  += su * wC;
            vv0  += b0 * wCv;
            vv1  += b1 * wCv;
            vv2  += b2 * wCv;
        }
    }
    scal *= A2_4;
    gat  *= A2_4;
    const float ve0 = (csv * sh0 + vv0) * A2_4;
    const float ve1 = (csv * sh1 + vv1) * A2_4;
    const float ve2 = (csv * sh2 + vv2) * A2_4;

    const float ts = tanhf(scal);
    const float tg = tanhf(gat);
    const float nn = nrm[ge];

    if (act) {
        if (ATOMIC) {
            float* ob = dst_buf + (size_t)dst * 32;
            atomicAdd(ob + j,             ts  * nn);
            atomicAdd(ob + 8 + 3 * j + 0, ve0 * tg * nn);
            atomicAdd(ob + 8 + 3 * j + 1, ve1 * tg * nn);
            atomicAdd(ob + 8 + 3 * j + 2, ve2 * tg * nn);
        } else {
            float* ob = dst_buf + (size_t)ge * 32;
            ob[j]             = ts  * nn;
            ob[8 + 3 * j + 0] = ve0 * tg * nn;
            ob[8 + 3 * j + 1] = ve1 * tg * nn;
            ob[8 + 3 * j + 2] = ve2 * tg * nn;
        }
    }
}

extern "C" void kernel_launch(void* const* d_in, const int* in_sizes, int n_in,
                              void* d_out, int out_size, void* d_ws, size_t ws_size,
                              hipStream_t stream) {
    const float* x    = (const float*)d_in[0];
    const int*   esrc = (const int*)  d_in[1];
    const int*   edst = (const int*)  d_in[2];
    const float* evec = (const float*)d_in[3];
    const float* emb  = (const float*)d_in[4];
    const float* nrm  = (const float*)d_in[5];
    const float* W1   = (const float*)d_in[7];
    const float* W2   = (const float*)d_in[8];
    const float* W3   = (const float*)d_in[9];
    const float* W4   = (const float*)d_in[10];
    float* out = (float*)d_out;

    const int E  = in_sizes[1];       // edge count
    const int NN = out_size / 32;     // node count
    const int grid = (E + EPB - 1) / EPB;

    // workspace layout
    const int NNp = 10240;            // padded node slots (NN <= 10240 assumed; checked below)
    size_t o_counts = 0;
    size_t o_off    = o_counts + (size_t)NNp * 4;
    size_t o_cur    = o_off    + (size_t)NNp * 4;
    size_t o_eidx   = o_cur    + (size_t)NNp * 4;
    size_t o_eout   = o_eidx   + (size_t)((E + 3) & ~3) * 4;
    size_t need     = o_eout   + (size_t)E * 32 * 4;

    if (NN <= NNp && ws_size >= need) {
        char* ws = (char*)d_ws;
        int*   counts  = (int*)  (ws + o_counts);
        int*   offsets = (int*)  (ws + o_off);
        int*   cursor  = (int*)  (ws + o_cur);
        int*   eidx    = (int*)  (ws + o_eidx);
        float* eout    = (float*)(ws + o_eout);

        zero_i32<<<(NN + 255) / 256, 256, 0, stream>>>(counts, NN);
        hist_dst<<<(E + 255) / 256, 256, 0, stream>>>(edst, counts, E);
        scan_offsets<<<1, 1024, 0, stream>>>(counts, offsets, cursor, NN);
        fill_csr<<<(E + 255) / 256, 256, 0, stream>>>(edst, cursor, eidx, E);
        eq_nlmp<0><<<grid, BLOCK, 0, stream>>>(x, esrc, edst, evec, emb, nrm,
                                               W1, W2, W3, W4, eout, E);
        gather_out<<<(NN + 7) / 8, 256, 0, stream>>>(eout, offsets, counts, eidx, out, NN);
    } else {
        // fallback: fp32 atomic scatter
        zero_f32<<<(out_size + 255) / 256, 256, 0, stream>>>(out, out_size);
        eq_nlmp<1><<<grid, BLOCK, 0, stream>>>(x, esrc, edst, evec, emb, nrm,
                                               W1, W2, W3, W4, out, E);
    }
}

// Round 3
// 148.292 us; speedup vs baseline: 2.1934x; 2.1934x over previous
//
#include <hip/hip_runtime.h>

// ---------------------------------------------------------------------------
// Fused equivariant NLMP, MI355X. Persistent blocks (weights staged once,
// fp16 in LDS, fp32-accum dot2), CSR scatter-free output, coalesced stores.
// ---------------------------------------------------------------------------

#define EPB   64          // edges per batch
#define BLOCK (EPB * 8)   // 512 threads
#define GRID_MAIN 512     // 2 blocks/CU

#define SQRT3_F      1.7320508075688772f
#define INV_SQRT3_F  0.5773502691896258f
#define INV_SQRT10_F 0.31622776601683794f
#define A1_4         0.044194173824159216f   // (1/sqrt(32)) * (1/4)
#define A2_4         0.0625f                 // (1/sqrt(16)) * (1/4)

typedef _Float16 f16;
typedef f16 f16x2 __attribute__((ext_vector_type(2)));
typedef f16 f16x8 __attribute__((ext_vector_type(8)));

__global__ void zero_i32(int* __restrict__ p, int n) {
    int i = blockIdx.x * blockDim.x + threadIdx.x;
    if (i < n) p[i] = 0;
}
__global__ void zero_f32(float* __restrict__ p, int n) {
    int i = blockIdx.x * blockDim.x + threadIdx.x;
    if (i < n) p[i] = 0.0f;
}

__global__ void hist_dst(const int* __restrict__ edst, int* __restrict__ counts, int E) {
    int e = blockIdx.x * blockDim.x + threadIdx.x;
    if (e < E) atomicAdd(&counts[edst[e]], 1);
}

// single-block exclusive scan over counts -> offsets (and cursor copy)
__global__ void scan_offsets(const int* __restrict__ counts, int* __restrict__ offsets,
                             int* __restrict__ cursor, int nn) {
    __shared__ int buf[1024];
    __shared__ int base_s;
    const int tid = threadIdx.x;
    if (tid == 0) base_s = 0;
    __syncthreads();
    for (int start = 0; start < nn; start += 1024) {
        const int i = start + tid;
        const int v = (i < nn) ? counts[i] : 0;
        buf[tid] = v;
        __syncthreads();
        #pragma unroll
        for (int off = 1; off < 1024; off <<= 1) {
            int t = (tid >= off) ? buf[tid - off] : 0;
            __syncthreads();
            buf[tid] += t;
            __syncthreads();
        }
        const int excl = buf[tid] - v + base_s;
        if (i < nn) { offsets[i] = excl; cursor[i] = excl; }
        __syncthreads();
        if (tid == 1023) base_s += buf[1023];
        __syncthreads();
    }
}

__global__ void fill_csr(const int* __restrict__ edst, int* __restrict__ cursor,
                         int* __restrict__ eidx, int E) {
    int e = blockIdx.x * blockDim.x + threadIdx.x;
    if (e < E) {
        int p = atomicAdd(&cursor[edst[e]], 1);
        eidx[p] = e;
    }
}

// 32 threads per node: coalesced 128B reads of edge_out, one plain store
__global__ void gather_out(const float* __restrict__ eout, const int* __restrict__ offsets,
                           const int* __restrict__ counts, const int* __restrict__ eidx,
                           float* __restrict__ out, int nn) {
    const int tid = threadIdx.x;
    const int n = blockIdx.x * 8 + (tid >> 5);
    const int t = tid & 31;
    if (n >= nn) return;
    const int beg = offsets[n];
    const int cnt = counts[n];
    float acc = 0.0f;
    for (int k = 0; k < cnt; ++k) {
        const int idx = eidx[beg + k];
        acc += eout[(size_t)idx * 32 + t];
    }
    out[(size_t)n * 32 + t] = acc;
}

// 16-wide fp16 dot with fp32 accumulate; h in regs (8x f16x2), w in LDS (32B).
static __device__ __forceinline__ float dot16h(const f16x2* __restrict__ hh,
                                               const f16* __restrict__ w) {
    union U { f16x8 v; f16x2 p[4]; };
    U a, b;
    a.v = *(const f16x8*)(w);
    b.v = *(const f16x8*)(w + 8);
    float s = 0.0f;
#if __has_builtin(__builtin_amdgcn_fdot2)
    s = __builtin_amdgcn_fdot2(hh[0], a.p[0], s, false);
    s = __builtin_amdgcn_fdot2(hh[1], a.p[1], s, false);
    s = __builtin_amdgcn_fdot2(hh[2], a.p[2], s, false);
    s = __builtin_amdgcn_fdot2(hh[3], a.p[3], s, false);
    s = __builtin_amdgcn_fdot2(hh[4], b.p[0], s, false);
    s = __builtin_amdgcn_fdot2(hh[5], b.p[1], s, false);
    s = __builtin_amdgcn_fdot2(hh[6], b.p[2], s, false);
    s = __builtin_amdgcn_fdot2(hh[7], b.p[3], s, false);
#else
    #pragma unroll
    for (int i = 0; i < 4; ++i) {
        s += (float)hh[i][0]   * (float)a.p[i][0] + (float)hh[i][1]   * (float)a.p[i][1];
        s += (float)hh[i+4][0] * (float)b.p[i][0] + (float)hh[i+4][1] * (float)b.p[i][1];
    }
#endif
    return s;
}

// ATOMIC=0: write per-edge outputs to eout[E][32]; ATOMIC=1: atomicAdd into out[N][32]
template <int ATOMIC>
__global__ void __launch_bounds__(BLOCK, 4) eq_nlmp(
    const float* __restrict__ x,        // [N,32]
    const int*   __restrict__ esrc,     // [E]
    const int*   __restrict__ edst,     // [E]
    const float* __restrict__ evec,     // [E,3]
    const float* __restrict__ emb,      // [E,10]
    const float* __restrict__ nrm,      // [E]
    const float* __restrict__ W1,       // [10,16]
    const float* __restrict__ W2,       // [16,512]
    const float* __restrict__ W3,       // [10,16]
    const float* __restrict__ W4,       // [16,384]
    float*       __restrict__ dst_buf,  // eout [E,32]  (or out [N,32] if ATOMIC)
    int E, int nbatch)
{
    // weights, staged once per (persistent) block
    __shared__ f16   sW2h[512 * 24];  // rows q=0..511 (transposed), stride 24 halves
    __shared__ f16   sW4h[384 * 24];
    __shared__ float sW1[160];
    __shared__ float sW3[160];
    // per-batch buffers
    __shared__ float sXP[EPB * 68];   // xs[0..31], xd at +32; also reused as sOUT
    __shared__ float sEM[EPB * 10];
    __shared__ float sSH[EPB * 3];
    __shared__ f16   sHh[EPB * 16];   // h1 then h2 (fp16)
    __shared__ float sST[EPB * 8];
    __shared__ float sVT[EPB * 24];

    const int tid = threadIdx.x;
    const int e   = tid >> 3;
    const int j   = tid & 7;

    // ---- stage weights once (fp32 -> fp16, transposed, stride 24) ----
    {
        const int q = tid;  // 512 threads == 512 columns of W2
        #pragma unroll
        for (int hp = 0; hp < 8; ++hp) {
            float lo = W2[(2 * hp) * 512 + q];
            float hi = W2[(2 * hp + 1) * 512 + q];
            *(f16x2*)&sW2h[q * 24 + 2 * hp] = (f16x2){(f16)lo, (f16)hi};
        }
        if (q < 384) {
            #pragma unroll
            for (int hp = 0; hp < 8; ++hp) {
                float lo = W4[(2 * hp) * 384 + q];
                float hi = W4[(2 * hp + 1) * 384 + q];
                *(f16x2*)&sW4h[q * 24 + 2 * hp] = (f16x2){(f16)lo, (f16)hi};
            }
        }
        if (tid < 160) { sW1[tid] = W1[tid]; sW3[tid] = W3[tid]; }
    }
    // first __syncthreads below covers weight visibility

    for (int b = blockIdx.x; b < nbatch; b += gridDim.x) {
        const int ge0 = b * EPB;
        int ge = ge0 + e;
        const bool act = (ge < E);
        if (!act) ge = E - 1;

        // ---- per-edge loads ----
        const int src = esrc[ge];
        const int dst = edst[ge];
        {
            const float4* xs4 = (const float4*)(x + (size_t)src * 32);
            const float4* xd4 = (const float4*)(x + (size_t)dst * 32);
            float4 a = xs4[j];
            float4 bq = xd4[j];
            *(float4*)&sXP[e * 68 + 4 * j]      = a;
            *(float4*)&sXP[e * 68 + 32 + 4 * j] = bq;
        }
        if (j < 5) {
            float2 t = *(const float2*)(emb + (size_t)ge * 10 + 2 * j);
            *(float2*)&sEM[e * 10 + 2 * j] = t;
        }
        if (j == 0) {
            float vx = evec[(size_t)ge * 3 + 0];
            float vy = evec[(size_t)ge * 3 + 1];
            float vz = evec[(size_t)ge * 3 + 2];
            float rn = sqrtf(vx * vx + vy * vy + vz * vz);
            sSH[e * 3 + 0] = SQRT3_F * vx / rn;
            sSH[e * 3 + 1] = SQRT3_F * vy / rn;
            sSH[e * 3 + 2] = SQRT3_F * vz / rn;
        }
        __syncthreads();   // also orders weight staging (iter 0) / sOUT reuse (iter >0)

        // ---- h1 = relu(emb @ W1 / sqrt(10)), stored fp16 ----
        #pragma unroll
        for (int t = 0; t < 2; ++t) {
            const int hid = j + 8 * t;
            float acc = 0.0f;
            #pragma unroll
            for (int i = 0; i < 10; ++i) acc += sEM[e * 10 + i] * sW1[i * 16 + hid];
            sHh[e * 16 + hid] = (f16)fmaxf(acc * INV_SQRT10_F, 0.0f);
        }
        __syncthreads();

        const float sh0 = sSH[e * 3 + 0], sh1 = sSH[e * 3 + 1], sh2 = sSH[e * 3 + 2];

        // ---- TP1 ----
        float sts = 0.0f, svs = 0.0f, vt0 = 0.0f, vt1 = 0.0f, vt2 = 0.0f;
        {
            union U { f16x8 v; f16x2 p[4]; };
            U ha, hb;
            ha.v = *(const f16x8*)&sHh[e * 16 + 0];
            hb.v = *(const f16x8*)&sHh[e * 16 + 8];
            f16x2 hh[8] = {ha.p[0], ha.p[1], ha.p[2], ha.p[3],
                           hb.p[0], hb.p[1], hb.p[2], hb.p[3]};
            #pragma unroll 4
            for (int u = 0; u < 16; ++u) {
                const int so = (u < 8) ? u : (u + 24);
                const int vo = (u < 8) ? (8 + 3 * u) : (16 + 3 * u);
                const float su = sXP[e * 68 + so];
                const float a0 = sXP[e * 68 + vo + 0];
                const float a1 = sXP[e * 68 + vo + 1];
                const float a2 = sXP[e * 68 + vo + 2];
                const float vd = (a0 * sh0 + a1 * sh1 + a2 * sh2) * INV_SQRT3_F;
                const f16* wb = &sW2h[(u * 8 + j) * 24];
                const float wss = dot16h(hh, wb);
                const float wvv = dot16h(hh, wb + 128 * 24);
                const float wsv = dot16h(hh, wb + 256 * 24);
                const float wvs = dot16h(hh, wb + 384 * 24);
                sts += su * wss + vd * wvv;
                svs += su * wsv;
                vt0 += a0 * wvs;
                vt1 += a1 * wvs;
                vt2 += a2 * wvs;
            }
        }
        sST[e * 8 + j] = sts * A1_4;
        sVT[e * 24 + 3 * j + 0] = (svs * sh0 + vt0) * A1_4;
        sVT[e * 24 + 3 * j + 1] = (svs * sh1 + vt1) * A1_4;
        sVT[e * 24 + 3 * j + 2] = (svs * sh2 + vt2) * A1_4;
        __syncthreads();

        // ---- h2 (overwrites sHh) ----
        #pragma unroll
        for (int t = 0; t < 2; ++t) {
            const int hid = j + 8 * t;
            float acc = 0.0f;
            #pragma unroll
            for (int i = 0; i < 10; ++i) acc += sEM[e * 10 + i] * sW3[i * 16 + hid];
            sHh[e * 16 + hid] = (f16)fmaxf(acc * INV_SQRT10_F, 0.0f);
        }
        __syncthreads();

        // ---- TP2 ----
        float scal = 0.0f, gat = 0.0f, csv = 0.0f, vv0 = 0.0f, vv1 = 0.0f, vv2 = 0.0f;
        {
            union U { f16x8 v; f16x2 p[4]; };
            U ha, hb;
            ha.v = *(const f16x8*)&sHh[e * 16 + 0];
            hb.v = *(const f16x8*)&sHh[e * 16 + 8];
            f16x2 hh[8] = {ha.p[0], ha.p[1], ha.p[2], ha.p[3],
                           hb.p[0], hb.p[1], hb.p[2], hb.p[3]};
            #pragma unroll 4
            for (int u = 0; u < 8; ++u) {
                const float su = sST[e * 8 + u];
                const float b0 = sVT[e * 24 + 3 * u + 0];
                const float b1 = sVT[e * 24 + 3 * u + 1];
                const float b2 = sVT[e * 24 + 3 * u + 2];
                const float vd = (b0 * sh0 + b1 * sh1 + b2 * sh2) * INV_SQRT3_F;
                const f16* wb = &sW4h[(u * 8 + j) * 24];
                const float wA  = dot16h(hh, wb);             // Ass
                const float wAv = dot16h(hh, wb +  64 * 24);  // Avv
                const float wB  = dot16h(hh, wb + 128 * 24);  // Bss
                const float wBv = dot16h(hh, wb + 192 * 24);  // Bvv
                const float wC  = dot16h(hh, wb + 256 * 24);  // Csv
                const float wCv = dot16h(hh, wb + 320 * 24);  // Cvs
                scal += su * wA + vd * wAv;
                gat  += su * wB + vd * wBv;
                csv  += su * wC;
                vv0  += b0 * wCv;
                vv1  += b1 * wCv;
                vv2  += b2 * wCv;
            }
        }
        scal *= A2_4;
        gat  *= A2_4;
        const float ve0 = (csv * sh0 + vv0) * A2_4;
        const float ve1 = (csv * sh1 + vv1) * A2_4;
        const float ve2 = (csv * sh2 + vv2) * A2_4;

        const float ts = tanhf(scal);
        const float tg = tanhf(gat);
        const float nn = nrm[ge];

        if (ATOMIC) {
            if (act) {
                float* ob = dst_buf + (size_t)dst * 32;
                atomicAdd(ob + j,             ts  * nn);
                atomicAdd(ob + 8 + 3 * j + 0, ve0 * tg * nn);
                atomicAdd(ob + 8 + 3 * j + 1, ve1 * tg * nn);
                atomicAdd(ob + 8 + 3 * j + 2, ve2 * tg * nn);
            }
            __syncthreads();  // before next-iter LDS reuse
        } else {
            // stage to LDS (reuse sXP), then fully-coalesced float4 stores
            float* sOUT = sXP;  // TP2 no longer reads sXP
            __syncthreads();    // ensure all TP1-phase sXP reads done (TP2 doesn't read it)
            sOUT[e * 32 + j]             = ts  * nn;
            sOUT[e * 32 + 8 + 3 * j + 0] = ve0 * tg * nn;
            sOUT[e * 32 + 8 + 3 * j + 1] = ve1 * tg * nn;
            sOUT[e * 32 + 8 + 3 * j + 2] = ve2 * tg * nn;
            __syncthreads();
            const int nvalid = E - ge0;
            if (nvalid >= EPB) {
                *(float4*)&dst_buf[(size_t)ge0 * 32 + tid * 4] = *(const float4*)&sOUT[tid * 4];
            } else {
                #pragma unroll
                for (int k = 0; k < 4; ++k) {
                    int idx = tid * 4 + k;
                    if ((idx >> 5) < nvalid) dst_buf[(size_t)ge0 * 32 + idx] = sOUT[idx];
                }
            }
            __syncthreads();  // before next-iter sXP overwrite
        }
    }
}

extern "C" void kernel_launch(void* const* d_in, const int* in_sizes, int n_in,
                              void* d_out, int out_size, void* d_ws, size_t ws_size,
                              hipStream_t stream) {
    const float* x    = (const float*)d_in[0];
    const int*   esrc = (const int*)  d_in[1];
    const int*   edst = (const int*)  d_in[2];
    const float* evec = (const float*)d_in[3];
    const float* emb  = (const float*)d_in[4];
    const float* nrm  = (const float*)d_in[5];
    const float* W1   = (const float*)d_in[7];
    const float* W2   = (const float*)d_in[8];
    const float* W3   = (const float*)d_in[9];
    const float* W4   = (const float*)d_in[10];
    float* out = (float*)d_out;

    const int E  = in_sizes[1];       // edge count
    const int NN = out_size / 32;     // node count
    const int nbatch = (E + EPB - 1) / EPB;
    const int grid = (nbatch < GRID_MAIN) ? nbatch : GRID_MAIN;

    // workspace layout
    const int NNp = 10240;
    size_t o_counts = 0;
    size_t o_off    = o_counts + (size_t)NNp * 4;
    size_t o_cur    = o_off    + (size_t)NNp * 4;
    size_t o_eidx   = o_cur    + (size_t)NNp * 4;
    size_t o_eout   = o_eidx   + (size_t)((E + 3) & ~3) * 4;
    size_t need     = o_eout   + (size_t)E * 32 * 4;

    if (NN <= NNp && ws_size >= need) {
        char* ws = (char*)d_ws;
        int*   counts  = (int*)  (ws + o_counts);
        int*   offsets = (int*)  (ws + o_off);
        int*   cursor  = (int*)  (ws + o_cur);
        int*   eidx    = (int*)  (ws + o_eidx);
        float* eout    = (float*)(ws + o_eout);

        zero_i32<<<(NN + 255) / 256, 256, 0, stream>>>(counts, NN);
        hist_dst<<<(E + 255) / 256, 256, 0, stream>>>(edst, counts, E);
        scan_offsets<<<1, 1024, 0, stream>>>(counts, offsets, cursor, NN);
        fill_csr<<<(E + 255) / 256, 256, 0, stream>>>(edst, cursor, eidx, E);
        eq_nlmp<0><<<grid, BLOCK, 0, stream>>>(x, esrc, edst, evec, emb, nrm,
                                               W1, W2, W3, W4, eout, E, nbatch);
        gather_out<<<(NN + 7) / 8, 256, 0, stream>>>(eout, offsets, counts, eidx, out, NN);
    } else {
        zero_f32<<<(out_size + 255) / 256, 256, 0, stream>>>(out, out_size);
        eq_nlmp<1><<<grid, BLOCK, 0, stream>>>(x, esrc, edst, evec, emb, nrm,
                                               W1, W2, W3, W4, out, E, nbatch);
    }
}

// Round 4
// 108.409 us; speedup vs baseline: 3.0003x; 1.3679x over previous
//
#include <hip/hip_runtime.h>

// ---------------------------------------------------------------------------
// Fused equivariant NLMP, MI355X.
// Main kernel: wave = output column j (uniform weights via scalar loads),
// lane = edge. Weights pre-converted to fp16 in workspace, laid out so each
// (u,j) needs one contiguous 128B/192B scalar-loaded row group.
// Output: rank-based CSR placement (full 128B line per edge), streaming gather.
// ---------------------------------------------------------------------------

#define EPB   64
#define BLOCK 512

#define SQRT3_F      1.7320508075688772f
#define INV_SQRT3_F  0.5773502691896258f
#define INV_SQRT10_F 0.31622776601683794f
#define A1_4         0.044194173824159216f   // (1/sqrt(32)) * (1/4)
#define A2_4         0.0625f                 // (1/sqrt(16)) * (1/4)

typedef _Float16 f16;
typedef f16 f16x2 __attribute__((ext_vector_type(2)));
typedef f16 f16x4 __attribute__((ext_vector_type(4)));
typedef f16 f16x8 __attribute__((ext_vector_type(8)));

__global__ void zero_i32(int* __restrict__ p, int n) {
    int i = blockIdx.x * blockDim.x + threadIdx.x;
    if (i < n) p[i] = 0;
}
__global__ void zero_f32(float* __restrict__ p, int n) {
    int i = blockIdx.x * blockDim.x + threadIdx.x;
    if (i < n) p[i] = 0.0f;
}

// counts histogram + per-edge rank within its destination bucket
__global__ void hist_rank(const int* __restrict__ edst, int* __restrict__ counts,
                          int* __restrict__ rank, int E) {
    int e = blockIdx.x * blockDim.x + threadIdx.x;
    if (e < E) rank[e] = atomicAdd(&counts[edst[e]], 1);
}

// single-block shuffle-based exclusive scan: counts -> offsets
__global__ void scan_offsets(const int* __restrict__ counts, int* __restrict__ offsets, int nn) {
    __shared__ int wsum[17];
    __shared__ int base_s;
    const int tid = threadIdx.x;
    const int lane = tid & 63, w = tid >> 6;
    if (tid == 0) base_s = 0;
    __syncthreads();
    for (int start = 0; start < nn; start += 1024) {
        const int i = start + tid;
        const int v = (i < nn) ? counts[i] : 0;
        int s = v;
        #pragma unroll
        for (int off = 1; off < 64; off <<= 1) {
            int t = __shfl_up(s, off, 64);
            if (lane >= off) s += t;
        }
        if (lane == 63) wsum[w] = s;
        __syncthreads();
        if (tid == 0) {
            int acc = 0;
            #pragma unroll
            for (int k = 0; k < 16; ++k) { int t = wsum[k]; wsum[k] = acc; acc += t; }
            wsum[16] = acc;
        }
        __syncthreads();
        const int excl = base_s + wsum[w] + s - v;
        if (i < nn) offsets[i] = excl;
        __syncthreads();
        if (tid == 0) base_s += wsum[16];
        __syncthreads();
    }
}

// convert fp32 weights to fp16 with (u,j)-grouped layout:
// W2h[((u*8+j)*4 + p)*16 + h] = W2[h][p*128 + u*8 + j]
// W4h[((u*8+j)*6 + p)*16 + h] = W4[h][p*64  + u*8 + j]
__global__ void conv_w(const float* __restrict__ W2, const float* __restrict__ W4,
                       f16* __restrict__ W2h, f16* __restrict__ W4h) {
    const int q = threadIdx.x;
    if (q < 512) {
        const int u = (q & 127) >> 3, j = q & 7, p = q >> 7;
        f16* dst = W2h + (((u * 8 + j) * 4) + p) * 16;
        #pragma unroll
        for (int h = 0; h < 16; ++h) dst[h] = (f16)W2[h * 512 + q];
    }
    if (q < 384) {
        const int p = q >> 6, r = q & 63;
        const int u = r >> 3, j = r & 7;
        f16* dst = W4h + (((u * 8 + j) * 6) + p) * 16;
        #pragma unroll
        for (int h = 0; h < 16; ++h) dst[h] = (f16)W4[h * 384 + q];
    }
}

// streaming gather: node n sums contiguous rows [off, off+cnt) of eout
__global__ void gather_out(const float* __restrict__ eout, const int* __restrict__ offsets,
                           const int* __restrict__ counts, float* __restrict__ out, int nn) {
    const int tid = threadIdx.x;
    const int n = blockIdx.x * 8 + (tid >> 5);
    const int t = tid & 31;
    if (n >= nn) return;
    const int beg = offsets[n];
    const int cnt = counts[n];
    float acc = 0.0f;
    for (int k = 0; k < cnt; ++k) acc += eout[(size_t)(beg + k) * 32 + t];
    out[(size_t)n * 32 + t] = acc;
}

// 16-wide fp16 dot, fp32 accumulate; h in regs, w via (scalar) pointer
static __device__ __forceinline__ float dot16h(const f16x2* __restrict__ hh,
                                               const f16* __restrict__ w) {
    union U { f16x8 v; f16x2 p[4]; };
    U a, b;
    a.v = *(const f16x8*)(w);
    b.v = *(const f16x8*)(w + 8);
    float s = 0.0f;
#if __has_builtin(__builtin_amdgcn_fdot2)
    s = __builtin_amdgcn_fdot2(hh[0], a.p[0], s, false);
    s = __builtin_amdgcn_fdot2(hh[1], a.p[1], s, false);
    s = __builtin_amdgcn_fdot2(hh[2], a.p[2], s, false);
    s = __builtin_amdgcn_fdot2(hh[3], a.p[3], s, false);
    s = __builtin_amdgcn_fdot2(hh[4], b.p[0], s, false);
    s = __builtin_amdgcn_fdot2(hh[5], b.p[1], s, false);
    s = __builtin_amdgcn_fdot2(hh[6], b.p[2], s, false);
    s = __builtin_amdgcn_fdot2(hh[7], b.p[3], s, false);
#else
    #pragma unroll
    for (int i = 0; i < 4; ++i) {
        s += (float)hh[i][0]   * (float)a.p[i][0] + (float)hh[i][1]   * (float)a.p[i][1];
        s += (float)hh[i+4][0] * (float)b.p[i][0] + (float)hh[i+4][1] * (float)b.p[i][1];
    }
#endif
    return s;
}

// ATOMIC=0: write edge line to eout[pos[e]]; ATOMIC=1: atomicAdd into out[N][32]
template <int ATOMIC>
__global__ void __launch_bounds__(BLOCK, 4) eq_nlmp(
    const float* __restrict__ x,        // [N,32]
    const int*   __restrict__ esrc,     // [E]
    const int*   __restrict__ edst,     // [E]
    const float* __restrict__ evec,     // [E,3]
    const float* __restrict__ emb,      // [E,10]
    const float* __restrict__ nrm,      // [E]
    const float* __restrict__ W1,       // [10,16] fp32
    const float* __restrict__ W3,       // [10,16] fp32
    const f16*   __restrict__ W2h,      // converted layout
    const f16*   __restrict__ W4h,      // converted layout
    const int*   __restrict__ offsets,  // [NN]   (unused if ATOMIC)
    const int*   __restrict__ rank,     // [E]    (unused if ATOMIC)
    float*       __restrict__ dst_buf,  // eout [E,32] (or out [N,32] if ATOMIC)
    int E)
{
    __shared__ float sXP[EPB * 65];   // per edge: xs[0..31] at c=0..31, xd at c=32..63; reused as sOUT
    __shared__ float sEM[EPB * 11];
    __shared__ float sSH[EPB * 3];
    __shared__ f16   sHh[EPB * 20];
    __shared__ float sST[EPB * 9];
    __shared__ float sVT[EPB * 29];
    __shared__ float sW1s[160];
    __shared__ float sW3s[160];
    __shared__ int   sPOS[EPB];
    __shared__ int   sDST[EPB];
    __shared__ float sNRM[EPB];

    const int tid = threadIdx.x;
    const int e   = tid >> 3;
    const int q   = tid & 7;
    const int ge0 = blockIdx.x * EPB;
    int ge = ge0 + e;
    const int nvalid = (E - ge0 < EPB) ? (E - ge0) : EPB;
    if (ge >= E) ge = E - 1;

    if (tid < 160) { sW1s[tid] = W1[tid]; sW3s[tid] = W3[tid]; }

    // ---- prelude: stage per-edge data ----
    {
        const int src = esrc[ge];
        const int dst = edst[ge];
        const float4* xs4 = (const float4*)(x + (size_t)src * 32);
        const float4* xd4 = (const float4*)(x + (size_t)dst * 32);
        float4 a = xs4[q], b = xd4[q];
        sXP[e * 65 +      4 * q + 0] = a.x;
        sXP[e * 65 +      4 * q + 1] = a.y;
        sXP[e * 65 +      4 * q + 2] = a.z;
        sXP[e * 65 +      4 * q + 3] = a.w;
        sXP[e * 65 + 32 + 4 * q + 0] = b.x;
        sXP[e * 65 + 32 + 4 * q + 1] = b.y;
        sXP[e * 65 + 32 + 4 * q + 2] = b.z;
        sXP[e * 65 + 32 + 4 * q + 3] = b.w;
        if (q < 5) {
            float2 t = *(const float2*)(emb + (size_t)ge * 10 + 2 * q);
            sEM[e * 11 + 2 * q]     = t.x;
            sEM[e * 11 + 2 * q + 1] = t.y;
        }
        if (q == 0) {
            float vx = evec[(size_t)ge * 3 + 0];
            float vy = evec[(size_t)ge * 3 + 1];
            float vz = evec[(size_t)ge * 3 + 2];
            float rn = sqrtf(vx * vx + vy * vy + vz * vz);
            sSH[e * 3 + 0] = SQRT3_F * vx / rn;
            sSH[e * 3 + 1] = SQRT3_F * vy / rn;
            sSH[e * 3 + 2] = SQRT3_F * vz / rn;
        }
        if (q == 1) sNRM[e] = nrm[ge];
        if (q == 2) {
            if (ATOMIC) sDST[e] = dst;
            else        sPOS[e] = offsets[dst] + rank[ge];
        }
    }
    __syncthreads();

    // ---- MLP1: thread (e,q) computes hid = q, q+8 ----
    #pragma unroll
    for (int t = 0; t < 2; ++t) {
        const int hid = q + 8 * t;
        float acc = 0.0f;
        #pragma unroll
        for (int i = 0; i < 10; ++i) acc += sEM[e * 11 + i] * sW1s[i * 16 + hid];
        sHh[e * 20 + hid] = (f16)fmaxf(acc * INV_SQRT10_F, 0.0f);
    }
    __syncthreads();

    // ---- switch roles: lane = edge, wave = output column j ----
    const int l  = tid & 63;
    const int js = __builtin_amdgcn_readfirstlane(tid >> 6);  // 0..7, wave-uniform

    const float sh0 = sSH[l * 3 + 0], sh1 = sSH[l * 3 + 1], sh2 = sSH[l * 3 + 2];

    union HU { f16x4 q4[4]; f16x2 p[8]; };
    HU H;
    #pragma unroll
    for (int k = 0; k < 4; ++k) H.q4[k] = *(const f16x4*)&sHh[l * 20 + 4 * k];

    // ---- TP1 ----
    float sts = 0.0f, svs = 0.0f, vt0 = 0.0f, vt1 = 0.0f, vt2 = 0.0f;
    #pragma unroll 2
    for (int u = 0; u < 16; ++u) {
        const int so = (u < 8) ? u : (u + 24);
        const int vo = (u < 8) ? (8 + 3 * u) : (16 + 3 * u);
        const float su = sXP[l * 65 + so];
        const float a0 = sXP[l * 65 + vo + 0];
        const float a1 = sXP[l * 65 + vo + 1];
        const float a2 = sXP[l * 65 + vo + 2];
        const float vd = (a0 * sh0 + a1 * sh1 + a2 * sh2) * INV_SQRT3_F;
        const f16* wb = W2h + (size_t)((u * 8 + js) * 4) * 16;   // 128 B, wave-uniform
        const float wss = dot16h(H.p, wb);
        const float wvv = dot16h(H.p, wb + 16);
        const float wsv = dot16h(H.p, wb + 32);
        const float wvs = dot16h(H.p, wb + 48);
        sts += su * wss + vd * wvv;
        svs += su * wsv;
        vt0 += a0 * wvs;
        vt1 += a1 * wvs;
        vt2 += a2 * wvs;
    }
    sST[l * 9 + js] = sts * A1_4;
    sVT[l * 29 + 3 * js + 0] = (svs * sh0 + vt0) * A1_4;
    sVT[l * 29 + 3 * js + 1] = (svs * sh1 + vt1) * A1_4;
    sVT[l * 29 + 3 * js + 2] = (svs * sh2 + vt2) * A1_4;
    __syncthreads();

    // ---- MLP2 (overwrites sHh) ----
    #pragma unroll
    for (int t = 0; t < 2; ++t) {
        const int hid = q + 8 * t;
        float acc = 0.0f;
        #pragma unroll
        for (int i = 0; i < 10; ++i) acc += sEM[e * 11 + i] * sW3s[i * 16 + hid];
        sHh[e * 20 + hid] = (f16)fmaxf(acc * INV_SQRT10_F, 0.0f);
    }
    __syncthreads();

    #pragma unroll
    for (int k = 0; k < 4; ++k) H.q4[k] = *(const f16x4*)&sHh[l * 20 + 4 * k];

    // ---- TP2 ----
    float scal = 0.0f, gat = 0.0f, csv = 0.0f, vv0 = 0.0f, vv1 = 0.0f, vv2 = 0.0f;
    #pragma unroll 2
    for (int u = 0; u < 8; ++u) {
        const float su = sST[l * 9 + u];
        const float b0 = sVT[l * 29 + 3 * u + 0];
        const float b1 = sVT[l * 29 + 3 * u + 1];
        const float b2 = sVT[l * 29 + 3 * u + 2];
        const float vd = (b0 * sh0 + b1 * sh1 + b2 * sh2) * INV_SQRT3_F;
        const f16* wb = W4h + (size_t)((u * 8 + js) * 6) * 16;   // 192 B, wave-uniform
        const float wA  = dot16h(H.p, wb);           // Ass
        const float wAv = dot16h(H.p, wb + 16);      // Avv
        const float wB  = dot16h(H.p, wb + 32);      // Bss
        const float wBv = dot16h(H.p, wb + 48);      // Bvv
        const float wC  = dot16h(H.p, wb + 64);      // Csv
        const float wCv = dot16h(H.p, wb + 80);      // Cvs
        scal += su * wA + vd * wAv;
        gat  += su * wB + vd * wBv;
        csv  += su * wC;
        vv0  += b0 * wCv;
        vv1  += b1 * wCv;
        vv2  += b2 * wCv;
    }
    scal *= A2_4;
    gat  *= A2_4;
    const float ve0 = (csv * sh0 + vv0) * A2_4;
    const float ve1 = (csv * sh1 + vv1) * A2_4;
    const float ve2 = (csv * sh2 + vv2) * A2_4;

    const float nn = sNRM[l];
    const float ts = tanhf(scal) * nn;
    const float tg = tanhf(gat) * nn;

    if (ATOMIC) {
        if (l < nvalid) {
            float* ob = dst_buf + (size_t)sDST[l] * 32;
            atomicAdd(ob + js,             ts);
            atomicAdd(ob + 8 + 3 * js + 0, ve0 * tg);
            atomicAdd(ob + 8 + 3 * js + 1, ve1 * tg);
            atomicAdd(ob + 8 + 3 * js + 2, ve2 * tg);
        }
    } else {
        // stage outputs in sXP (safe: last sXP reads were 2 barriers ago)
        float* sOUT = sXP;
        sOUT[l * 65 + js]             = ts;
        sOUT[l * 65 + 8 + 3 * js + 0] = ve0 * tg;
        sOUT[l * 65 + 8 + 3 * js + 1] = ve1 * tg;
        sOUT[l * 65 + 8 + 3 * js + 2] = ve2 * tg;
        __syncthreads();
        // one full 128B line per edge at its CSR slot
        if (e < nvalid) {
            float4 v;
            v.x = sOUT[e * 65 + 4 * q + 0];
            v.y = sOUT[e * 65 + 4 * q + 1];
            v.z = sOUT[e * 65 + 4 * q + 2];
            v.w = sOUT[e * 65 + 4 * q + 3];
            *(float4*)&dst_buf[(size_t)sPOS[e] * 32 + 4 * q] = v;
        }
    }
}

extern "C" void kernel_launch(void* const* d_in, const int* in_sizes, int n_in,
                              void* d_out, int out_size, void* d_ws, size_t ws_size,
                              hipStream_t stream) {
    const float* x    = (const float*)d_in[0];
    const int*   esrc = (const int*)  d_in[1];
    const int*   edst = (const int*)  d_in[2];
    const float* evec = (const float*)d_in[3];
    const float* emb  = (const float*)d_in[4];
    const float* nrm  = (const float*)d_in[5];
    const float* W1   = (const float*)d_in[7];
    const float* W2   = (const float*)d_in[8];
    const float* W3   = (const float*)d_in[9];
    const float* W4   = (const float*)d_in[10];
    float* out = (float*)d_out;

    const int E  = in_sizes[1];
    const int NN = out_size / 32;
    const int nbatch = (E + EPB - 1) / EPB;

    // workspace layout (all offsets 64B-aligned)
    const int NNp = 10240;
    size_t o_w2h   = 0;                                   // 512*16*2  = 16384
    size_t o_w4h   = o_w2h + 512 * 16 * 2;                // 384*16*2  = 12288
    size_t o_cnt   = o_w4h + 384 * 16 * 2;                // NNp*4
    size_t o_off   = o_cnt + (size_t)NNp * 4;
    size_t o_rank  = o_off + (size_t)NNp * 4;
    size_t o_eout  = (o_rank + (size_t)E * 4 + 255) & ~(size_t)255;
    size_t need    = o_eout + (size_t)E * 128;

    char* ws = (char*)d_ws;
    f16* W2h = (f16*)(ws + o_w2h);
    f16* W4h = (f16*)(ws + o_w4h);

    conv_w<<<1, 512, 0, stream>>>(W2, W4, W2h, W4h);

    if (NN <= NNp && ws_size >= need) {
        int*   counts  = (int*)  (ws + o_cnt);
        int*   offsets = (int*)  (ws + o_off);
        int*   rank    = (int*)  (ws + o_rank);
        float* eout    = (float*)(ws + o_eout);

        zero_i32<<<(NN + 255) / 256, 256, 0, stream>>>(counts, NN);
        hist_rank<<<(E + 255) / 256, 256, 0, stream>>>(edst, counts, rank, E);
        scan_offsets<<<1, 1024, 0, stream>>>(counts, offsets, NN);
        eq_nlmp<0><<<nbatch, BLOCK, 0, stream>>>(x, esrc, edst, evec, emb, nrm,
                                                 W1, W3, W2h, W4h, offsets, rank, eout, E);
        gather_out<<<(NN + 7) / 8, 256, 0, stream>>>(eout, offsets, counts, out, NN);
    } else {
        zero_f32<<<(out_size + 255) / 256, 256, 0, stream>>>(out, out_size);
        eq_nlmp<1><<<nbatch, BLOCK, 0, stream>>>(x, esrc, edst, evec, emb, nrm,
                                                 W1, W3, W2h, W4h, nullptr, nullptr, out, E);
    }
}

// Round 5
// 103.322 us; speedup vs baseline: 3.1481x; 1.0492x over previous
//
#include <hip/hip_runtime.h>

// ---------------------------------------------------------------------------
// Fused equivariant NLMP, MI355X.
// Main kernel: wave = output column j (uniform scalar-loaded weights),
// lane = edge. Per-edge data packed so each TP u-step is one ds_read_b128.
// 4 blocks/CU via launch_bounds(512,8). CSR rank placement + streaming gather.
// ---------------------------------------------------------------------------

#define EPB   64
#define BLOCK 512
#define NNP   10240

#define SQRT3_F      1.7320508075688772f
#define INV_SQRT3_F  0.5773502691896258f
#define INV_SQRT10_F 0.31622776601683794f
#define A1_4         0.044194173824159216f   // (1/sqrt(32)) * (1/4)
#define A2_4         0.0625f                 // (1/sqrt(16)) * (1/4)

typedef _Float16 f16;
typedef f16 f16x2 __attribute__((ext_vector_type(2)));
typedef f16 f16x4 __attribute__((ext_vector_type(4)));
typedef f16 f16x8 __attribute__((ext_vector_type(8)));

__global__ void zero_f32(float* __restrict__ p, int n) {
    int i = blockIdx.x * blockDim.x + threadIdx.x;
    if (i < n) p[i] = 0.0f;
}

// fused: zero counts + convert weights to fp16 (u,j)-grouped layout
__global__ void prep(const float* __restrict__ W2, const float* __restrict__ W4,
                     f16* __restrict__ W2h, f16* __restrict__ W4h,
                     int* __restrict__ counts, int NN) {
    int gid = blockIdx.x * blockDim.x + threadIdx.x;
    if (gid < NN) counts[gid] = 0;
    if (gid >= NNP && gid < NNP + 8192) {
        int idx = gid - NNP;
        int q = idx >> 4, h = idx & 15;
        int u = (q & 127) >> 3, j = q & 7, p = q >> 7;
        W2h[(((u * 8 + j) * 4) + p) * 16 + h] = (f16)W2[h * 512 + q];
    } else if (gid >= NNP + 8192 && gid < NNP + 8192 + 6144) {
        int idx = gid - NNP - 8192;
        int q = idx >> 4, h = idx & 15;
        int p = q >> 6, r = q & 63;
        int u = r >> 3, j = r & 7;
        W4h[(((u * 8 + j) * 6) + p) * 16 + h] = (f16)W4[h * 384 + q];
    }
}

__global__ void hist_rank(const int* __restrict__ edst, int* __restrict__ counts,
                          int* __restrict__ rank, int E) {
    int e = blockIdx.x * blockDim.x + threadIdx.x;
    if (e < E) rank[e] = atomicAdd(&counts[edst[e]], 1);
}

__global__ void scan_offsets(const int* __restrict__ counts, int* __restrict__ offsets, int nn) {
    __shared__ int wsum[17];
    __shared__ int base_s;
    const int tid = threadIdx.x;
    const int lane = tid & 63, w = tid >> 6;
    if (tid == 0) base_s = 0;
    __syncthreads();
    for (int start = 0; start < nn; start += 1024) {
        const int i = start + tid;
        const int v = (i < nn) ? counts[i] : 0;
        int s = v;
        #pragma unroll
        for (int off = 1; off < 64; off <<= 1) {
            int t = __shfl_up(s, off, 64);
            if (lane >= off) s += t;
        }
        if (lane == 63) wsum[w] = s;
        __syncthreads();
        if (tid == 0) {
            int acc = 0;
            #pragma unroll
            for (int k = 0; k < 16; ++k) { int t = wsum[k]; wsum[k] = acc; acc += t; }
            wsum[16] = acc;
        }
        __syncthreads();
        const int excl = base_s + wsum[w] + s - v;
        if (i < nn) offsets[i] = excl;
        __syncthreads();
        if (tid == 0) base_s += wsum[16];
        __syncthreads();
    }
}

__global__ void gather_out(const float* __restrict__ eout, const int* __restrict__ offsets,
                           const int* __restrict__ counts, float* __restrict__ out, int nn) {
    const int tid = threadIdx.x;
    const int n = blockIdx.x * 8 + (tid >> 5);
    const int t = tid & 31;
    if (n >= nn) return;
    const int beg = offsets[n];
    const int cnt = counts[n];
    float acc = 0.0f;
    for (int k = 0; k < cnt; ++k) acc += eout[(size_t)(beg + k) * 32 + t];
    out[(size_t)n * 32 + t] = acc;
}

static __device__ __forceinline__ float dot16h(const f16x2* __restrict__ hh,
                                               const f16* __restrict__ w) {
    union U { f16x8 v; f16x2 p[4]; };
    U a, b;
    a.v = *(const f16x8*)(w);
    b.v = *(const f16x8*)(w + 8);
    float s = 0.0f;
#if __has_builtin(__builtin_amdgcn_fdot2)
    s = __builtin_amdgcn_fdot2(hh[0], a.p[0], s, false);
    s = __builtin_amdgcn_fdot2(hh[1], a.p[1], s, false);
    s = __builtin_amdgcn_fdot2(hh[2], a.p[2], s, false);
    s = __builtin_amdgcn_fdot2(hh[3], a.p[3], s, false);
    s = __builtin_amdgcn_fdot2(hh[4], b.p[0], s, false);
    s = __builtin_amdgcn_fdot2(hh[5], b.p[1], s, false);
    s = __builtin_amdgcn_fdot2(hh[6], b.p[2], s, false);
    s = __builtin_amdgcn_fdot2(hh[7], b.p[3], s, false);
#else
    #pragma unroll
    for (int i = 0; i < 4; ++i) {
        s += (float)hh[i][0]   * (float)a.p[i][0] + (float)hh[i][1]   * (float)a.p[i][1];
        s += (float)hh[i+4][0] * (float)b.p[i][0] + (float)hh[i+4][1] * (float)b.p[i][1];
    }
#endif
    return s;
}

static __device__ __forceinline__ float tanh_fast(float x) {
    x = fminf(fmaxf(x, -15.0f), 15.0f);
    float e = __expf(2.0f * x);
    return (e - 1.0f) * __builtin_amdgcn_rcpf(e + 1.0f);
}

// ATOMIC=0: write edge line to eout[pos[e]]; ATOMIC=1: atomicAdd into out[N][32]
template <int ATOMIC>
__global__ void __launch_bounds__(BLOCK, 8) eq_nlmp(
    const float* __restrict__ x,        // [N,32]
    const int*   __restrict__ esrc,     // [E]
    const int*   __restrict__ edst,     // [E]
    const float* __restrict__ evec,     // [E,3]
    const float* __restrict__ emb,      // [E,10]
    const float* __restrict__ nrm,      // [E]
    const float* __restrict__ W1,       // [10,16] fp32
    const float* __restrict__ W3,       // [10,16] fp32
    const f16*   __restrict__ W2h,
    const f16*   __restrict__ W4h,
    const int*   __restrict__ offsets,
    const int*   __restrict__ rank,
    float*       __restrict__ dst_buf,
    int E)
{
    __shared__ float sXP [EPB * 68];   // per edge u=0..15: [su,a0,a1,a2]; reused as sOUT
    __shared__ float sSTVT[EPB * 36];  // per edge u=0..7: [st,vt0,vt1,vt2]
    __shared__ float sEM [EPB * 12];
    __shared__ float sSH [EPB * 3];
    __shared__ f16   sH1 [EPB * 20];
    __shared__ f16   sH2 [EPB * 20];
    __shared__ float sW1t[16 * 12];    // transposed [hid][i]
    __shared__ float sW3t[16 * 12];
    __shared__ int   sPOS[EPB];
    __shared__ int   sDST[EPB];
    __shared__ float sNRM[EPB];

    const int tid = threadIdx.x;
    const int e   = tid >> 3;
    const int q   = tid & 7;
    const int ge0 = blockIdx.x * EPB;
    int ge = ge0 + e;
    const int nvalid = (E - ge0 < EPB) ? (E - ge0) : EPB;
    if (ge >= E) ge = E - 1;

    if (tid < 160) {
        const int row = tid >> 4, hid = tid & 15;   // W1[row][hid]
        sW1t[hid * 12 + row] = W1[tid];
        sW3t[hid * 12 + row] = W3[tid];
    }

    // ---- prelude: gather + repack per-edge data ----
    {
        const int src = esrc[ge];
        const int dst = edst[ge];
        const float4* xs4 = (const float4*)(x + (size_t)src * 32);
        const float4* xd4 = (const float4*)(x + (size_t)dst * 32);
        float4 a = xs4[q], b = xd4[q];
        float av[4] = {a.x, a.y, a.z, a.w};
        float bv[4] = {b.x, b.y, b.z, b.w};
        #pragma unroll
        for (int m = 0; m < 4; ++m) {
            const int i = 4 * q + m;
            // xs element i
            {
                int pos;
                if (i < 8) pos = 4 * i;
                else { int r = i - 8; int u = (r * 2731) >> 13; pos = 4 * u + 1 + (r - 3 * u); }
                sXP[e * 68 + pos] = av[m];
            }
            // xd element i
            {
                int pos;
                if (i < 8) pos = 4 * (8 + i);
                else { int r = i - 8; int u = (r * 2731) >> 13; pos = 4 * (8 + u) + 1 + (r - 3 * u); }
                sXP[e * 68 + pos] = bv[m];
            }
        }
        if (q < 5) {
            float2 t = *(const float2*)(emb + (size_t)ge * 10 + 2 * q);
            sEM[e * 12 + 2 * q]     = t.x;
            sEM[e * 12 + 2 * q + 1] = t.y;
        }
        if (q == 0) {
            float vx = evec[(size_t)ge * 3 + 0];
            float vy = evec[(size_t)ge * 3 + 1];
            float vz = evec[(size_t)ge * 3 + 2];
            float rn = sqrtf(vx * vx + vy * vy + vz * vz);
            sSH[e * 3 + 0] = SQRT3_F * vx / rn;
            sSH[e * 3 + 1] = SQRT3_F * vy / rn;
            sSH[e * 3 + 2] = SQRT3_F * vz / rn;
        }
        if (q == 1) sNRM[e] = nrm[ge];
        if (q == 2) {
            if (ATOMIC) sDST[e] = dst;
            else        sPOS[e] = offsets[dst] + rank[ge];
        }
    }
    __syncthreads();

    // ---- MLP1 + MLP2 together: thread (e,q) computes hid = q, q+8 for both ----
    {
        float2 em0 = *(const float2*)&sEM[e * 12 + 0];
        float2 em1 = *(const float2*)&sEM[e * 12 + 2];
        float2 em2 = *(const float2*)&sEM[e * 12 + 4];
        float2 em3 = *(const float2*)&sEM[e * 12 + 6];
        float2 em4 = *(const float2*)&sEM[e * 12 + 8];
        #pragma unroll
        for (int t = 0; t < 2; ++t) {
            const int hid = q + 8 * t;
            {
                const float4 wa = *(const float4*)&sW1t[hid * 12 + 0];
                const float4 wb = *(const float4*)&sW1t[hid * 12 + 4];
                const float2 wc = *(const float2*)&sW1t[hid * 12 + 8];
                float acc = em0.x*wa.x + em0.y*wa.y + em1.x*wa.z + em1.y*wa.w
                          + em2.x*wb.x + em2.y*wb.y + em3.x*wb.z + em3.y*wb.w
                          + em4.x*wc.x + em4.y*wc.y;
                sH1[e * 20 + hid] = (f16)fmaxf(acc * INV_SQRT10_F, 0.0f);
            }
            {
                const float4 wa = *(const float4*)&sW3t[hid * 12 + 0];
                const float4 wb = *(const float4*)&sW3t[hid * 12 + 4];
                const float2 wc = *(const float2*)&sW3t[hid * 12 + 8];
                float acc = em0.x*wa.x + em0.y*wa.y + em1.x*wa.z + em1.y*wa.w
                          + em2.x*wb.x + em2.y*wb.y + em3.x*wb.z + em3.y*wb.w
                          + em4.x*wc.x + em4.y*wc.y;
                sH2[e * 20 + hid] = (f16)fmaxf(acc * INV_SQRT10_F, 0.0f);
            }
        }
    }
    __syncthreads();

    // ---- role switch: lane = edge, wave = output column j ----
    const int l  = tid & 63;
    const int js = __builtin_amdgcn_readfirstlane(tid >> 6);

    const float sh0 = sSH[l * 3 + 0], sh1 = sSH[l * 3 + 1], sh2 = sSH[l * 3 + 2];

    union HU { f16x4 q4[4]; f16x2 p[8]; };
    HU H;
    #pragma unroll
    for (int k = 0; k < 4; ++k) H.q4[k] = *(const f16x4*)&sH1[l * 20 + 4 * k];

    // ---- TP1 ----
    float sts = 0.0f, svs = 0.0f, vt0 = 0.0f, vt1 = 0.0f, vt2 = 0.0f;
    #pragma unroll 2
    for (int u = 0; u < 16; ++u) {
        const float4 d = *(const float4*)&sXP[l * 68 + 4 * u];   // [su,a0,a1,a2]
        const float vd = (d.y * sh0 + d.z * sh1 + d.w * sh2) * INV_SQRT3_F;
        const f16* wb = W2h + (size_t)((u * 8 + js) * 4) * 16;   // 128 B, wave-uniform
        const float wss = dot16h(H.p, wb);
        const float wvv = dot16h(H.p, wb + 16);
        const float wsv = dot16h(H.p, wb + 32);
        const float wvs = dot16h(H.p, wb + 48);
        sts += d.x * wss + vd * wvv;
        svs += d.x * wsv;
        vt0 += d.y * wvs;
        vt1 += d.z * wvs;
        vt2 += d.w * wvs;
    }
    {
        float4 stvt;
        stvt.x = sts * A1_4;
        stvt.y = (svs * sh0 + vt0) * A1_4;
        stvt.z = (svs * sh1 + vt1) * A1_4;
        stvt.w = (svs * sh2 + vt2) * A1_4;
        *(float4*)&sSTVT[l * 36 + 4 * js] = stvt;
    }
    __syncthreads();

    #pragma unroll
    for (int k = 0; k < 4; ++k) H.q4[k] = *(const f16x4*)&sH2[l * 20 + 4 * k];

    // ---- TP2 ----
    float scal = 0.0f, gat = 0.0f, csv = 0.0f, vv0 = 0.0f, vv1 = 0.0f, vv2 = 0.0f;
    #pragma unroll 2
    for (int u = 0; u < 8; ++u) {
        const float4 d = *(const float4*)&sSTVT[l * 36 + 4 * u];  // [st,vt0,vt1,vt2]
        const float vd = (d.y * sh0 + d.z * sh1 + d.w * sh2) * INV_SQRT3_F;
        const f16* wb = W4h + (size_t)((u * 8 + js) * 6) * 16;    // 192 B, wave-uniform
        const float wA  = dot16h(H.p, wb);
        const float wAv = dot16h(H.p, wb + 16);
        const float wB  = dot16h(H.p, wb + 32);
        const float wBv = dot16h(H.p, wb + 48);
        const float wC  = dot16h(H.p, wb + 64);
        const float wCv = dot16h(H.p, wb + 80);
        scal += d.x * wA + vd * wAv;
        gat  += d.x * wB + vd * wBv;
        csv  += d.x * wC;
        vv0  += d.y * wCv;
        vv1  += d.z * wCv;
        vv2  += d.w * wCv;
    }
    scal *= A2_4;
    gat  *= A2_4;
    const float ve0 = (csv * sh0 + vv0) * A2_4;
    const float ve1 = (csv * sh1 + vv1) * A2_4;
    const float ve2 = (csv * sh2 + vv2) * A2_4;

    const float nn = sNRM[l];
    const float ts = tanh_fast(scal) * nn;
    const float tg = tanh_fast(gat) * nn;

    if (ATOMIC) {
        if (l < nvalid) {
            float* ob = dst_buf + (size_t)sDST[l] * 32;
            atomicAdd(ob + js,             ts);
            atomicAdd(ob + 8 + 3 * js + 0, ve0 * tg);
            atomicAdd(ob + 8 + 3 * js + 1, ve1 * tg);
            atomicAdd(ob + 8 + 3 * js + 2, ve2 * tg);
        }
    } else {
        // stage outputs into sXP (all TP1 reads completed before STVT barrier)
        float* sOUT = sXP;
        sOUT[l * 68 + js]             = ts;
        sOUT[l * 68 + 8 + 3 * js + 0] = ve0 * tg;
        sOUT[l * 68 + 8 + 3 * js + 1] = ve1 * tg;
        sOUT[l * 68 + 8 + 3 * js + 2] = ve2 * tg;
        __syncthreads();
        if (e < nvalid) {
            float4 v = *(const float4*)&sOUT[e * 68 + 4 * q];
            *(float4*)&dst_buf[(size_t)sPOS[e] * 32 + 4 * q] = v;
        }
    }
}

extern "C" void kernel_launch(void* const* d_in, const int* in_sizes, int n_in,
                              void* d_out, int out_size, void* d_ws, size_t ws_size,
                              hipStream_t stream) {
    const float* x    = (const float*)d_in[0];
    const int*   esrc = (const int*)  d_in[1];
    const int*   edst = (const int*)  d_in[2];
    const float* evec = (const float*)d_in[3];
    const float* emb  = (const float*)d_in[4];
    const float* nrm  = (const float*)d_in[5];
    const float* W1   = (const float*)d_in[7];
    const float* W2   = (const float*)d_in[8];
    const float* W3   = (const float*)d_in[9];
    const float* W4   = (const float*)d_in[10];
    float* out = (float*)d_out;

    const int E  = in_sizes[1];
    const int NN = out_size / 32;
    const int nbatch = (E + EPB - 1) / EPB;

    size_t o_w2h   = 0;
    size_t o_w4h   = o_w2h + 512 * 16 * 2;
    size_t o_cnt   = o_w4h + 384 * 16 * 2;
    size_t o_off   = o_cnt + (size_t)NNP * 4;
    size_t o_rank  = o_off + (size_t)NNP * 4;
    size_t o_eout  = (o_rank + (size_t)E * 4 + 255) & ~(size_t)255;
    size_t need    = o_eout + (size_t)E * 128;

    char* ws = (char*)d_ws;
    f16* W2h = (f16*)(ws + o_w2h);
    f16* W4h = (f16*)(ws + o_w4h);
    int*   counts  = (int*)  (ws + o_cnt);
    int*   offsets = (int*)  (ws + o_off);
    int*   rank    = (int*)  (ws + o_rank);
    float* eout    = (float*)(ws + o_eout);

    const int prep_threads = NNP + 8192 + 6144;
    prep<<<(prep_threads + 255) / 256, 256, 0, stream>>>(W2, W4, W2h, W4h, counts, NN);

    if (NN <= NNP && ws_size >= need) {
        hist_rank<<<(E + 255) / 256, 256, 0, stream>>>(edst, counts, rank, E);
        scan_offsets<<<1, 1024, 0, stream>>>(counts, offsets, NN);
        eq_nlmp<0><<<nbatch, BLOCK, 0, stream>>>(x, esrc, edst, evec, emb, nrm,
                                                 W1, W3, W2h, W4h, offsets, rank, eout, E);
        gather_out<<<(NN + 7) / 8, 256, 0, stream>>>(eout, offsets, counts, out, NN);
    } else {
        zero_f32<<<(out_size + 255) / 256, 256, 0, stream>>>(out, out_size);
        eq_nlmp<1><<<nbatch, BLOCK, 0, stream>>>(x, esrc, edst, evec, emb, nrm,
                                                 W1, W3, W2h, W4h, nullptr, nullptr, out, E);
    }
}